// Round 11
// baseline (679.500 us; speedup 1.0000x reference)
//
#include <hip/hip_runtime.h>
#include <hip/hip_bf16.h>
#include <stdint.h>

// ---------------- types ----------------
typedef __bf16 bf16x8 __attribute__((ext_vector_type(8)));
typedef float  f32x4  __attribute__((ext_vector_type(4)));

#define BM 128
#define BN 128
#define BK 32

// fast transcendentals: v_exp_f32-based, rel err ~1e-6 (bf16 pipeline noise
// floor is ~4e-3, so this is invisible in absmax).
__device__ __forceinline__ float fsig(float x) {
  return 1.f / (1.f + exp2f(-1.44269504f * x));
}
__device__ __forceinline__ float ftanh(float x) {
  return 2.f / (1.f + exp2f(-2.88539008f * x)) - 1.f;
}

// async global->LDS, 16B per lane. LDS dest must be wave-uniform base; data
// lands at base + lane*16.
__device__ __forceinline__ void gld_lds16(const __hip_bfloat16* g, __hip_bfloat16* l) {
  __builtin_amdgcn_global_load_lds(
      (const __attribute__((address_space(1))) void*)g,
      (__attribute__((address_space(3))) void*)l, 16, 0, 0);
}

// ---------------- GEMM: C = [A0|A1] @ Bt^T + bias ----------
// A parts bf16 row-major [M,K1] (stride lda0) / [M,K2] (stride lda1).
// Bt bf16 [N,Ktot] row-major (B transposed; rows gate-permuted for mode 1).
// mode 0: C fp32 [M,ldc] = z + bias (optional relu).
// mode 1 (LSTM): Bt rows permuted as r=(u>>4)*64+gate*16+(u&15); epilogue
//   computes cstate/h in place: c=sig(f)*c+sig(i)*tanh(g); h=sig(o)*tanh(c);
//   h (bf16) -> hout[row*1024+coff+u], c (fp32) -> cstate[row*512+u].
// Requires: M%128==0, N%128==0, K1%32==0, K2%32==0.
__global__ __launch_bounds__(256) void gemm_bt(
    const __hip_bfloat16* __restrict__ A0, int lda0, int K1,
    const __hip_bfloat16* __restrict__ A1, int lda1, int K2,
    const __hip_bfloat16* __restrict__ Bt,
    const float* __restrict__ bias,
    float* __restrict__ C, int ldc, int doRelu,
    int mode, float* __restrict__ cstate,
    __hip_bfloat16* __restrict__ hout, int coff)
{
  const int Ktot = K1 + K2;
  __shared__ __align__(16) __hip_bfloat16 As[BM * BK];
  __shared__ __align__(16) __hip_bfloat16 Bs[BN * BK];

  const int tid = threadIdx.x;
  const int w = tid >> 6;        // wave 0..3
  const int l = tid & 63;        // lane
  const int m0 = blockIdx.x * BM;
  const int n0 = blockIdx.y * BN;

  // staging: chunk c covers 16 tile rows; lane covers 8 contiguous k elems
  const int r0 = w * 16 + (l >> 2);
  const int r1 = r0 + 64;
  const int cst = (l & 3) * 8;

  // mfma fragment mapping (16x16x32)
  const int wm = (w >> 1) * 64, wn = (w & 1) * 64;
  const int lrow = l & 15;
  const int lk = (l >> 4) * 8;

  f32x4 acc[4][4];
#pragma unroll
  for (int mt = 0; mt < 4; ++mt)
#pragma unroll
    for (int nt = 0; nt < 4; ++nt)
      acc[mt][nt] = (f32x4){0.f, 0.f, 0.f, 0.f};

  for (int k0 = 0; k0 < Ktot; k0 += BK) {
    const __hip_bfloat16* Ab;
    long lda;
    if (k0 < K1) { Ab = A0 + k0;        lda = lda0; }
    else         { Ab = A1 + (k0 - K1); lda = lda1; }
    const __hip_bfloat16* Bb = Bt + k0;

    __syncthreads();
    gld_lds16(Ab + (long)(m0 + r0) * lda + cst, &As[(size_t)w * 512]);
    gld_lds16(Ab + (long)(m0 + r1) * lda + cst, &As[(size_t)(w + 4) * 512]);
    gld_lds16(Bb + (long)(n0 + r0) * Ktot + cst, &Bs[(size_t)w * 512]);
    gld_lds16(Bb + (long)(n0 + r1) * Ktot + cst, &Bs[(size_t)(w + 4) * 512]);
    __syncthreads();

    bf16x8 af[4], bfr[4];
#pragma unroll
    for (int mt = 0; mt < 4; ++mt)
      af[mt] = *(const bf16x8*)&As[(wm + mt * 16 + lrow) * BK + lk];
#pragma unroll
    for (int nt = 0; nt < 4; ++nt)
      bfr[nt] = *(const bf16x8*)&Bs[(wn + nt * 16 + lrow) * BK + lk];
#pragma unroll
    for (int mt = 0; mt < 4; ++mt)
#pragma unroll
      for (int nt = 0; nt < 4; ++nt)
        acc[mt][nt] = __builtin_amdgcn_mfma_f32_16x16x32_bf16(
            af[mt], bfr[nt], acc[mt][nt], 0, 0, 0);
  }

  // C/D fragment layout: row = (l>>4)*4 + j, col = l&15 (guide-verified)
  const int crb = (l >> 4) * 4;
  const int ccol = l & 15;

  if (mode == 1) {
    // gate fusion: nt is the gate (i,f,g,o); u fixed per thread
    const int ublock = (n0 + wn) >> 6;
    const int u = (ublock << 4) | ccol;
    const float bi = bias[u];
    const float bff = bias[512 + u];
    const float bg = bias[1024 + u];
    const float bo = bias[1536 + u];
#pragma unroll
    for (int mt = 0; mt < 4; ++mt) {
#pragma unroll
      for (int j = 0; j < 4; ++j) {
        const int row = m0 + wm + mt * 16 + crb + j;  // batch index
        const float zi = acc[mt][0][j] + bi;
        const float zf = acc[mt][1][j] + bff;
        const float zg = acc[mt][2][j] + bg;
        const float zo = acc[mt][3][j] + bo;
        const float si = fsig(zi);
        const float sf = fsig(zf);
        const float so = fsig(zo);
        float cc = cstate[(long)row * 512 + u];
        cc = sf * cc + si * ftanh(zg);
        cstate[(long)row * 512 + u] = cc;
        hout[(long)row * 1024 + coff + u] = __float2bfloat16(so * ftanh(cc));
      }
    }
    return;
  }

#pragma unroll
  for (int nt = 0; nt < 4; ++nt) {
    const int col = n0 + wn + nt * 16 + ccol;
    const float bv = bias ? bias[col] : 0.f;
#pragma unroll
    for (int mt = 0; mt < 4; ++mt) {
#pragma unroll
      for (int j = 0; j < 4; ++j) {
        const int row = m0 + wm + mt * 16 + crb + j;
        float v = acc[mt][nt][j] + bv;
        if (doRelu) v = fmaxf(v, 0.f);
        C[(long)row * ldc + col] = v;
      }
    }
  }
}

// ------- transpose fp32 [K,N] -> bf16 [row(n), ldo] at col offset kofs ------
// permuteGates: row(n) = ((n&511)>>4)*64 + (n>>9)*16 + (n&15), else row(n)=n.
__global__ __launch_bounds__(256) void transpose_bf16_kernel(
    const float* __restrict__ in, int K, int N,
    __hip_bfloat16* __restrict__ out, int ldo, int kofs, int permuteGates)
{
  __shared__ float tile[32][33];
  const int kb = blockIdx.x * 32, nb = blockIdx.y * 32;
  const int tx = threadIdx.x & 31, ty = threadIdx.x >> 5;  // 32 x 8
#pragma unroll
  for (int i = ty; i < 32; i += 8) {
    int k = kb + i, n = nb + tx;
    tile[i][tx] = (k < K && n < N) ? in[(long)k * N + n] : 0.f;
  }
  __syncthreads();
#pragma unroll
  for (int i = ty; i < 32; i += 8) {
    int n = nb + i, k = kb + tx;
    if (n < N && k < K) {
      int r = permuteGates ? (((n & 511) >> 4) * 64 + (n >> 9) * 16 + (n & 15))
                           : n;
      out[(long)r * ldo + kofs + k] = __float2bfloat16(tile[tx][i]);
    }
  }
}

// ---------------- conv1 (7x3, 3->10) + relu + maxpool3 over W ---------------
// x [4096,15,80,3] -> out [4096,9,26,10] fp32
// weight-register blocking: wv[10] in VGPRs -> 30 FMA per 10-float LDS read.
__global__ __launch_bounds__(256) void conv1_pool_kernel(
    const float* __restrict__ x, const float* __restrict__ w,
    const float* __restrict__ bias, float* __restrict__ out)
{
  __shared__ float ws[630];
  __shared__ float bs[10];
  for (int i = threadIdx.x; i < 630; i += 256) ws[i] = w[i];
  if (threadIdx.x < 10) bs[threadIdx.x] = bias[threadIdx.x];
  __syncthreads();

  const int idx = blockIdx.x * 256 + threadIdx.x;
  const int owp = idx % 26;
  const int t1 = idx / 26;
  const int oh = t1 % 9;
  const int b = t1 / 9;
  if (b >= 4096) return;

  float acc[3][10];
#pragma unroll
  for (int p = 0; p < 3; ++p)
#pragma unroll
    for (int co = 0; co < 10; ++co) acc[p][co] = 0.f;

  const float* xbase = x + ((long)(b * 15 + oh) * 80 + owp * 3) * 3;
  for (int kh = 0; kh < 7; ++kh) {
    const float* xr = xbase + kh * 240;
    float xv[15];
#pragma unroll
    for (int i = 0; i < 15; ++i) xv[i] = xr[i];
#pragma unroll
    for (int kw = 0; kw < 3; ++kw) {
#pragma unroll
      for (int ci = 0; ci < 3; ++ci) {
        const float* wr = &ws[((kh * 3 + kw) * 3 + ci) * 10];
        float wv[10];
#pragma unroll
        for (int co = 0; co < 10; ++co) wv[co] = wr[co];
#pragma unroll
        for (int p = 0; p < 3; ++p) {
          const float v = xv[(p + kw) * 3 + ci];
#pragma unroll
          for (int co = 0; co < 10; ++co)
            acc[p][co] = fmaf(v, wv[co], acc[p][co]);
        }
      }
    }
  }
  float* op = out + ((long)(b * 9 + oh) * 26 + owp) * 10;
#pragma unroll
  for (int co = 0; co < 10; ++co) {
    float m = fmaxf(fmaxf(acc[0][co], acc[1][co]), acc[2][co]);
    op[co] = fmaxf(m + bs[co], 0.f);
  }
}

// ---------------- conv2 (3x3, 10->20) + relu + maxpool3 -> bf16 seq ---------
// in [4096,9,26,10] -> seq [4096,7,160] bf16 (feature = w*20 + c)
__global__ __launch_bounds__(256) void conv2_pool_kernel(
    const float* __restrict__ in, const float* __restrict__ w,
    const float* __restrict__ bias, __hip_bfloat16* __restrict__ seq)
{
  __shared__ float ws[1800];
  __shared__ float bs[20];
  for (int i = threadIdx.x; i < 1800; i += 256) ws[i] = w[i];
  if (threadIdx.x < 20) bs[threadIdx.x] = bias[threadIdx.x];
  __syncthreads();

  const int idx = blockIdx.x * 256 + threadIdx.x;
  const int owp = idx & 7;
  const int t1 = idx >> 3;
  const int oh = t1 % 7;
  const int b = t1 / 7;
  if (b >= 4096) return;

  float acc[3][20];
#pragma unroll
  for (int p = 0; p < 3; ++p)
#pragma unroll
    for (int co = 0; co < 20; ++co) acc[p][co] = 0.f;

  const float* ibase = in + ((long)(b * 9 + oh) * 26 + owp * 3) * 10;
  for (int kh = 0; kh < 3; ++kh) {
    const float* ir = ibase + kh * 260;
    float xv[50];
#pragma unroll
    for (int i = 0; i < 50; ++i) xv[i] = ir[i];
#pragma unroll
    for (int kw = 0; kw < 3; ++kw) {
#pragma unroll
      for (int ci = 0; ci < 10; ++ci) {
        const float* wr = &ws[((kh * 3 + kw) * 10 + ci) * 20];
        float wv[20];
#pragma unroll
        for (int co = 0; co < 20; ++co) wv[co] = wr[co];
#pragma unroll
        for (int p = 0; p < 3; ++p) {
          const float v = xv[(p + kw) * 10 + ci];
#pragma unroll
          for (int co = 0; co < 20; ++co)
            acc[p][co] = fmaf(v, wv[co], acc[p][co]);
        }
      }
    }
  }
  __hip_bfloat16* op = seq + (long)(b * 7 + oh) * 160 + owp * 20;
#pragma unroll
  for (int co = 0; co < 20; ++co) {
    float m = fmaxf(fmaxf(acc[0][co], acc[1][co]), acc[2][co]);
    op[co] = __float2bfloat16(fmaxf(m + bs[co], 0.f));
  }
}

// ---------------- host ------------------------------------------------------
extern "C" void kernel_launch(void* const* d_in, const int* in_sizes, int n_in,
                              void* d_out, int out_size, void* d_ws, size_t ws_size,
                              hipStream_t stream) {
  const float* x    = (const float*)d_in[0];
  const float* c1w  = (const float*)d_in[1];
  const float* c1b  = (const float*)d_in[2];
  const float* c2w  = (const float*)d_in[3];
  const float* c2b  = (const float*)d_in[4];
  const float* W1   = (const float*)d_in[5];
  const float* U1   = (const float*)d_in[6];
  const float* b1   = (const float*)d_in[7];
  const float* W2   = (const float*)d_in[8];
  const float* U2   = (const float*)d_in[9];
  const float* b2   = (const float*)d_in[10];
  const float* fcw  = (const float*)d_in[11];
  const float* fcb  = (const float*)d_in[12];
  float* out = (float*)d_out;

  char* ws = (char*)d_ws;
  // workspace layout, total 63,111,168 B (~60.2 MiB).
  // pool1 (conv1 output, 38.3 MB) is DEAD after conv2; c1s/c2s/hA all alias
  // it and are first touched by memsets enqueued AFTER conv2 in stream order.
  float*          pool1 = (float*)(ws + 0);                 // 38,338,560 B [4096,9,26,10]
  float*          c1s   = (float*)(ws + 0);                 //  8,388,608 B [4096][512] (alias)
  float*          c2s   = (float*)(ws + 8388608);           //  8,388,608 B [4096][512] (alias)
  __hip_bfloat16* hA    = (__hip_bfloat16*)(ws + 16777216); //  8,388,608 B [4096][1024] (alias)
  __hip_bfloat16* seq   = (__hip_bfloat16*)(ws + 38338560); //  9,175,040 B [4096,7,160]
  __hip_bfloat16* Wt1   = (__hip_bfloat16*)(ws + 47513600); //  2,752,512 B [2048][672] gate-permuted
  __hip_bfloat16* Wt2   = (__hip_bfloat16*)(ws + 50266112); //  4,194,304 B [2048][1024] gate-permuted
  __hip_bfloat16* fcwt  = (__hip_bfloat16*)(ws + 54460416); //    262,144 B [256][512]
  __hip_bfloat16* hB    = (__hip_bfloat16*)(ws + 54722560); //  8,388,608 B ping-pong partner

  // weight prep: bf16 transposed [N,K] rows, LSTM weights gate-permuted
  transpose_bf16_kernel<<<dim3(5, 64), 256, 0, stream>>>(W1, 160, 2048, Wt1, 672, 0, 1);
  transpose_bf16_kernel<<<dim3(16, 64), 256, 0, stream>>>(U1, 512, 2048, Wt1, 672, 160, 1);
  transpose_bf16_kernel<<<dim3(16, 64), 256, 0, stream>>>(W2, 512, 2048, Wt2, 1024, 0, 1);
  transpose_bf16_kernel<<<dim3(16, 64), 256, 0, stream>>>(U2, 512, 2048, Wt2, 1024, 512, 1);
  transpose_bf16_kernel<<<dim3(16, 8), 256, 0, stream>>>(fcw, 512, 256, fcwt, 512, 0, 0);

  // convs (pool1 dead after conv2)
  conv1_pool_kernel<<<3744, 256, 0, stream>>>(x, c1w, c1b, pool1);
  conv2_pool_kernel<<<896, 256, 0, stream>>>(pool1, c2w, c2b, seq);

  // zero initial LSTM state (all alias dead pool1; stream-ordered after conv2;
  // c1s+c2s contiguous -> single 16 MB memset)
  hipMemsetAsync(c1s, 0, 2 * 4096 * 512 * sizeof(float), stream);
  hipMemsetAsync(hA, 0, 4096 * 1024 * sizeof(__hip_bfloat16), stream);

  // LSTM: 7 steps, 2 stacked cells, gates fused into GEMM epilogue.
  // Ping-pong h buffers (GEMM reads hprev while writing hnext -> no race;
  // cell2 reads hnext[:,0:512] written by the PREVIOUS dispatch and writes
  // hnext[:,512:1024] -> disjoint).
  for (int t = 0; t < 7; ++t) {
    __hip_bfloat16* hprev = (t & 1) ? hB : hA;
    __hip_bfloat16* hnext = (t & 1) ? hA : hB;
    // cell1: z = [x_t | h1_prev] @ Wt1^T + b1 -> h1_new, c1
    gemm_bt<<<dim3(32, 16), 256, 0, stream>>>(
        seq + t * 160, 1120, 160, hprev, 1024, 512, Wt1, b1,
        nullptr, 0, 0, 1, c1s, hnext, 0);
    // cell2: z = [h1_new | h2_prev] @ Wt2^T + b2 -> h2_new, c2
    gemm_bt<<<dim3(32, 16), 256, 0, stream>>>(
        hnext, 1024, 512, hprev + 512, 1024, 512, Wt2, b2,
        nullptr, 0, 0, 1, c2s, hnext, 512);
  }

  // final h2 lives in hB (t=6 even -> hnext == hB)
  gemm_bt<<<dim3(32, 2), 256, 0, stream>>>(
      hB + 512, 1024, 512, (const __hip_bfloat16*)nullptr, 0, 0,
      fcwt, fcb, out, 256, 1, 0, nullptr, nullptr, 0);
}

// Round 12
// 660.336 us; speedup vs baseline: 1.0290x; 1.0290x over previous
//
#include <hip/hip_runtime.h>
#include <hip/hip_bf16.h>
#include <stdint.h>

// ---------------- types ----------------
typedef __bf16 bf16x8 __attribute__((ext_vector_type(8)));
typedef float  f32x4  __attribute__((ext_vector_type(4)));

#define BM 128
#define BN 128
#define BK 32

// fast transcendentals: v_exp_f32-based, rel err ~1e-6 (verified: absmax
// unchanged at 9.77e-4 vs libm version).
__device__ __forceinline__ float fsig(float x) {
  return 1.f / (1.f + exp2f(-1.44269504f * x));
}
__device__ __forceinline__ float ftanh(float x) {
  return 2.f / (1.f + exp2f(-2.88539008f * x)) - 1.f;
}

// async global->LDS, 16B per lane. LDS dest must be wave-uniform base; data
// lands at base + lane*16.
__device__ __forceinline__ void gld_lds16(const __hip_bfloat16* g, __hip_bfloat16* l) {
  __builtin_amdgcn_global_load_lds(
      (const __attribute__((address_space(1))) void*)g,
      (__attribute__((address_space(3))) void*)l, 16, 0, 0);
}

// ---------------- GEMM: C = [A0|A1] @ Bt^T + bias ----------
// A parts bf16 row-major [M,K1] (stride lda0) / [M,K2] (stride lda1).
// Bt bf16 [N,Ktot] row-major (B transposed; rows gate-permuted for mode 1).
// mode 0: C fp32 [M,ldc] = z + bias (optional relu).
// mode 1 (LSTM): Bt rows permuted as r=(u>>4)*64+gate*16+(u&15); epilogue
//   computes cstate/h in place: c=sig(f)*c+sig(i)*tanh(g); h=sig(o)*tanh(c);
//   h (bf16) -> hout[row*1024+coff+u], c (fp32) -> cstate[row*512+u].
// Requires: M%128==0, N%128==0, K1%32==0, K2%32==0.
__global__ __launch_bounds__(256) void gemm_bt(
    const __hip_bfloat16* __restrict__ A0, int lda0, int K1,
    const __hip_bfloat16* __restrict__ A1, int lda1, int K2,
    const __hip_bfloat16* __restrict__ Bt,
    const float* __restrict__ bias,
    float* __restrict__ C, int ldc, int doRelu,
    int mode, float* __restrict__ cstate,
    __hip_bfloat16* __restrict__ hout, int coff)
{
  const int Ktot = K1 + K2;
  __shared__ __align__(16) __hip_bfloat16 As[BM * BK];
  __shared__ __align__(16) __hip_bfloat16 Bs[BN * BK];

  const int tid = threadIdx.x;
  const int w = tid >> 6;        // wave 0..3
  const int l = tid & 63;        // lane
  const int m0 = blockIdx.x * BM;
  const int n0 = blockIdx.y * BN;

  // staging: chunk c covers 16 tile rows; lane covers 8 contiguous k elems
  const int r0 = w * 16 + (l >> 2);
  const int r1 = r0 + 64;
  const int cst = (l & 3) * 8;

  // mfma fragment mapping (16x16x32)
  const int wm = (w >> 1) * 64, wn = (w & 1) * 64;
  const int lrow = l & 15;
  const int lk = (l >> 4) * 8;

  f32x4 acc[4][4];
#pragma unroll
  for (int mt = 0; mt < 4; ++mt)
#pragma unroll
    for (int nt = 0; nt < 4; ++nt)
      acc[mt][nt] = (f32x4){0.f, 0.f, 0.f, 0.f};

  for (int k0 = 0; k0 < Ktot; k0 += BK) {
    const __hip_bfloat16* Ab;
    long lda;
    if (k0 < K1) { Ab = A0 + k0;        lda = lda0; }
    else         { Ab = A1 + (k0 - K1); lda = lda1; }
    const __hip_bfloat16* Bb = Bt + k0;

    __syncthreads();
    gld_lds16(Ab + (long)(m0 + r0) * lda + cst, &As[(size_t)w * 512]);
    gld_lds16(Ab + (long)(m0 + r1) * lda + cst, &As[(size_t)(w + 4) * 512]);
    gld_lds16(Bb + (long)(n0 + r0) * Ktot + cst, &Bs[(size_t)w * 512]);
    gld_lds16(Bb + (long)(n0 + r1) * Ktot + cst, &Bs[(size_t)(w + 4) * 512]);
    __syncthreads();

    bf16x8 af[4], bfr[4];
#pragma unroll
    for (int mt = 0; mt < 4; ++mt)
      af[mt] = *(const bf16x8*)&As[(wm + mt * 16 + lrow) * BK + lk];
#pragma unroll
    for (int nt = 0; nt < 4; ++nt)
      bfr[nt] = *(const bf16x8*)&Bs[(wn + nt * 16 + lrow) * BK + lk];
#pragma unroll
    for (int mt = 0; mt < 4; ++mt)
#pragma unroll
      for (int nt = 0; nt < 4; ++nt)
        acc[mt][nt] = __builtin_amdgcn_mfma_f32_16x16x32_bf16(
            af[mt], bfr[nt], acc[mt][nt], 0, 0, 0);
  }

  // C/D fragment layout: row = (l>>4)*4 + j, col = l&15 (guide-verified)
  const int crb = (l >> 4) * 4;
  const int ccol = l & 15;

  if (mode == 1) {
    // gate fusion: nt is the gate (i,f,g,o); u fixed per thread
    const int ublock = (n0 + wn) >> 6;
    const int u = (ublock << 4) | ccol;
    const float bi = bias[u];
    const float bff = bias[512 + u];
    const float bg = bias[1024 + u];
    const float bo = bias[1536 + u];
#pragma unroll
    for (int mt = 0; mt < 4; ++mt) {
#pragma unroll
      for (int j = 0; j < 4; ++j) {
        const int row = m0 + wm + mt * 16 + crb + j;  // batch index
        const float zi = acc[mt][0][j] + bi;
        const float zf = acc[mt][1][j] + bff;
        const float zg = acc[mt][2][j] + bg;
        const float zo = acc[mt][3][j] + bo;
        const float si = fsig(zi);
        const float sf = fsig(zf);
        const float so = fsig(zo);
        float cc = cstate[(long)row * 512 + u];
        cc = sf * cc + si * ftanh(zg);
        cstate[(long)row * 512 + u] = cc;
        hout[(long)row * 1024 + coff + u] = __float2bfloat16(so * ftanh(cc));
      }
    }
    return;
  }

#pragma unroll
  for (int nt = 0; nt < 4; ++nt) {
    const int col = n0 + wn + nt * 16 + ccol;
    const float bv = bias ? bias[col] : 0.f;
#pragma unroll
    for (int mt = 0; mt < 4; ++mt) {
#pragma unroll
      for (int j = 0; j < 4; ++j) {
        const int row = m0 + wm + mt * 16 + crb + j;
        float v = acc[mt][nt][j] + bv;
        if (doRelu) v = fmaxf(v, 0.f);
        C[(long)row * ldc + col] = v;
      }
    }
  }
}

// ------- transpose fp32 [K,N] -> bf16 [row(n), ldo] at col offset kofs ------
// permuteGates: row(n) = ((n&511)>>4)*64 + (n>>9)*16 + (n&15), else row(n)=n.
__global__ __launch_bounds__(256) void transpose_bf16_kernel(
    const float* __restrict__ in, int K, int N,
    __hip_bfloat16* __restrict__ out, int ldo, int kofs, int permuteGates)
{
  __shared__ float tile[32][33];
  const int kb = blockIdx.x * 32, nb = blockIdx.y * 32;
  const int tx = threadIdx.x & 31, ty = threadIdx.x >> 5;  // 32 x 8
#pragma unroll
  for (int i = ty; i < 32; i += 8) {
    int k = kb + i, n = nb + tx;
    tile[i][tx] = (k < K && n < N) ? in[(long)k * N + n] : 0.f;
  }
  __syncthreads();
#pragma unroll
  for (int i = ty; i < 32; i += 8) {
    int n = nb + i, k = kb + tx;
    if (n < N && k < K) {
      int r = permuteGates ? (((n & 511) >> 4) * 64 + (n >> 9) * 16 + (n & 15))
                           : n;
      out[(long)r * ldo + kofs + k] = __float2bfloat16(tile[tx][i]);
    }
  }
}

// ---------------- conv1 (7x3, 3->10) + relu + maxpool3 over W ---------------
// x [4096,15,80,3] -> out [4096,9,26,10] fp32
// v2: one block per image; stage the 14.4 KB image into LDS with coalesced
// float4 loads (fixes 36B-lane-stride scalar global loads = ~36 cache lines
// per wave-load, the round-11 measured bottleneck: VALUBusy 44%, HBM 16%).
// Compute reads LDS; summation order per output unchanged -> bit-identical.
__global__ __launch_bounds__(256) void conv1_pool_kernel(
    const float* __restrict__ x, const float* __restrict__ w,
    const float* __restrict__ bias, float* __restrict__ out)
{
  __shared__ float xs[3600];   // 15 x 80 x 3
  __shared__ float ws[630];
  __shared__ float bs[10];
  const int b = blockIdx.x;

  const float4* xg = (const float4*)(x + (long)b * 3600);
  float4* xs4 = (float4*)xs;
  for (int i = threadIdx.x; i < 900; i += 256) xs4[i] = xg[i];
  for (int i = threadIdx.x; i < 630; i += 256) ws[i] = w[i];
  if (threadIdx.x < 10) bs[threadIdx.x] = bias[threadIdx.x];
  __syncthreads();

  const int t = threadIdx.x;
  if (t >= 234) return;               // 9 x 26 pooled positions
  const int owp = t % 26;
  const int oh = t / 26;

  float acc[3][10];
#pragma unroll
  for (int p = 0; p < 3; ++p)
#pragma unroll
    for (int co = 0; co < 10; ++co) acc[p][co] = 0.f;

  const float* xbase = &xs[oh * 240 + owp * 9];
  for (int kh = 0; kh < 7; ++kh) {
    const float* xr = xbase + kh * 240;
    float xv[15];
#pragma unroll
    for (int i = 0; i < 15; ++i) xv[i] = xr[i];
#pragma unroll
    for (int kw = 0; kw < 3; ++kw) {
#pragma unroll
      for (int ci = 0; ci < 3; ++ci) {
        const float* wr = &ws[((kh * 3 + kw) * 3 + ci) * 10];
        float wv[10];
#pragma unroll
        for (int co = 0; co < 10; ++co) wv[co] = wr[co];
#pragma unroll
        for (int p = 0; p < 3; ++p) {
          const float v = xv[(p + kw) * 3 + ci];
#pragma unroll
          for (int co = 0; co < 10; ++co)
            acc[p][co] = fmaf(v, wv[co], acc[p][co]);
        }
      }
    }
  }
  float* op = out + ((long)(b * 9 + oh) * 26 + owp) * 10;
#pragma unroll
  for (int co = 0; co < 10; ++co) {
    float m = fmaxf(fmaxf(acc[0][co], acc[1][co]), acc[2][co]);
    op[co] = fmaxf(m + bs[co], 0.f);
  }
}

// ---------------- conv2 (3x3, 10->20) + relu + maxpool3 -> bf16 seq ---------
// in [4096,9,26,10] -> seq [4096,7,160] bf16 (feature = w*20 + c)
// v2: block handles 4 images staged into LDS (37.4 KB) with coalesced float4
// loads (old version: 120B lane stride on pool1 reads).
__global__ __launch_bounds__(256) void conv2_pool_kernel(
    const float* __restrict__ in, const float* __restrict__ w,
    const float* __restrict__ bias, __hip_bfloat16* __restrict__ seq)
{
  __shared__ float xs[9360];   // 4 x (9 x 26 x 10)
  __shared__ float ws[1800];
  __shared__ float bs[20];
  const int b0 = blockIdx.x * 4;

  const float4* ig = (const float4*)(in + (long)b0 * 2340);
  float4* xs4 = (float4*)xs;
  for (int i = threadIdx.x; i < 2340; i += 256) xs4[i] = ig[i];
  for (int i = threadIdx.x; i < 1800; i += 256) ws[i] = w[i];
  if (threadIdx.x < 20) bs[threadIdx.x] = bias[threadIdx.x];
  __syncthreads();

  const int t = threadIdx.x;
  if (t >= 224) return;               // 4 images x (7 x 8) positions
  const int img = t / 56;
  const int pos = t % 56;
  const int oh = pos >> 3;
  const int owp = pos & 7;
  const int b = b0 + img;

  float acc[3][20];
#pragma unroll
  for (int p = 0; p < 3; ++p)
#pragma unroll
    for (int co = 0; co < 20; ++co) acc[p][co] = 0.f;

  const float* ibase = &xs[img * 2340 + oh * 260 + owp * 30];
  for (int kh = 0; kh < 3; ++kh) {
    const float* ir = ibase + kh * 260;
    float xv[50];
#pragma unroll
    for (int i = 0; i < 50; ++i) xv[i] = ir[i];
#pragma unroll
    for (int kw = 0; kw < 3; ++kw) {
#pragma unroll
      for (int ci = 0; ci < 10; ++ci) {
        const float* wr = &ws[((kh * 3 + kw) * 10 + ci) * 20];
        float wv[20];
#pragma unroll
        for (int co = 0; co < 20; ++co) wv[co] = wr[co];
#pragma unroll
        for (int p = 0; p < 3; ++p) {
          const float v = xv[(p + kw) * 10 + ci];
#pragma unroll
          for (int co = 0; co < 20; ++co)
            acc[p][co] = fmaf(v, wv[co], acc[p][co]);
        }
      }
    }
  }
  __hip_bfloat16* op = seq + (long)(b * 7 + oh) * 160 + owp * 20;
#pragma unroll
  for (int co = 0; co < 20; ++co) {
    float m = fmaxf(fmaxf(acc[0][co], acc[1][co]), acc[2][co]);
    op[co] = __float2bfloat16(fmaxf(m + bs[co], 0.f));
  }
}

// ---------------- host ------------------------------------------------------
extern "C" void kernel_launch(void* const* d_in, const int* in_sizes, int n_in,
                              void* d_out, int out_size, void* d_ws, size_t ws_size,
                              hipStream_t stream) {
  const float* x    = (const float*)d_in[0];
  const float* c1w  = (const float*)d_in[1];
  const float* c1b  = (const float*)d_in[2];
  const float* c2w  = (const float*)d_in[3];
  const float* c2b  = (const float*)d_in[4];
  const float* W1   = (const float*)d_in[5];
  const float* U1   = (const float*)d_in[6];
  const float* b1   = (const float*)d_in[7];
  const float* W2   = (const float*)d_in[8];
  const float* U2   = (const float*)d_in[9];
  const float* b2   = (const float*)d_in[10];
  const float* fcw  = (const float*)d_in[11];
  const float* fcb  = (const float*)d_in[12];
  float* out = (float*)d_out;

  char* ws = (char*)d_ws;
  // workspace layout, total 63,111,168 B (~60.2 MiB).
  // pool1 (conv1 output, 38.3 MB) is DEAD after conv2; c1s/c2s/hA all alias
  // it and are first touched by memsets enqueued AFTER conv2 in stream order.
  float*          pool1 = (float*)(ws + 0);                 // 38,338,560 B [4096,9,26,10]
  float*          c1s   = (float*)(ws + 0);                 //  8,388,608 B [4096][512] (alias)
  float*          c2s   = (float*)(ws + 8388608);           //  8,388,608 B [4096][512] (alias)
  __hip_bfloat16* hA    = (__hip_bfloat16*)(ws + 16777216); //  8,388,608 B [4096][1024] (alias)
  __hip_bfloat16* seq   = (__hip_bfloat16*)(ws + 38338560); //  9,175,040 B [4096,7,160]
  __hip_bfloat16* Wt1   = (__hip_bfloat16*)(ws + 47513600); //  2,752,512 B [2048][672] gate-permuted
  __hip_bfloat16* Wt2   = (__hip_bfloat16*)(ws + 50266112); //  4,194,304 B [2048][1024] gate-permuted
  __hip_bfloat16* fcwt  = (__hip_bfloat16*)(ws + 54460416); //    262,144 B [256][512]
  __hip_bfloat16* hB    = (__hip_bfloat16*)(ws + 54722560); //  8,388,608 B ping-pong partner

  // weight prep: bf16 transposed [N,K] rows, LSTM weights gate-permuted
  transpose_bf16_kernel<<<dim3(5, 64), 256, 0, stream>>>(W1, 160, 2048, Wt1, 672, 0, 1);
  transpose_bf16_kernel<<<dim3(16, 64), 256, 0, stream>>>(U1, 512, 2048, Wt1, 672, 160, 1);
  transpose_bf16_kernel<<<dim3(16, 64), 256, 0, stream>>>(W2, 512, 2048, Wt2, 1024, 0, 1);
  transpose_bf16_kernel<<<dim3(16, 64), 256, 0, stream>>>(U2, 512, 2048, Wt2, 1024, 512, 1);
  transpose_bf16_kernel<<<dim3(16, 8), 256, 0, stream>>>(fcw, 512, 256, fcwt, 512, 0, 0);

  // convs (pool1 dead after conv2)
  conv1_pool_kernel<<<4096, 256, 0, stream>>>(x, c1w, c1b, pool1);
  conv2_pool_kernel<<<1024, 256, 0, stream>>>(pool1, c2w, c2b, seq);

  // zero initial LSTM state (all alias dead pool1; stream-ordered after conv2;
  // c1s+c2s contiguous -> single 16 MB memset)
  hipMemsetAsync(c1s, 0, 2 * 4096 * 512 * sizeof(float), stream);
  hipMemsetAsync(hA, 0, 4096 * 1024 * sizeof(__hip_bfloat16), stream);

  // LSTM: 7 steps, 2 stacked cells, gates fused into GEMM epilogue.
  // Ping-pong h buffers (GEMM reads hprev while writing hnext -> no race;
  // cell2 reads hnext[:,0:512] written by the PREVIOUS dispatch and writes
  // hnext[:,512:1024] -> disjoint).
  for (int t = 0; t < 7; ++t) {
    __hip_bfloat16* hprev = (t & 1) ? hB : hA;
    __hip_bfloat16* hnext = (t & 1) ? hA : hB;
    // cell1: z = [x_t | h1_prev] @ Wt1^T + b1 -> h1_new, c1
    gemm_bt<<<dim3(32, 16), 256, 0, stream>>>(
        seq + t * 160, 1120, 160, hprev, 1024, 512, Wt1, b1,
        nullptr, 0, 0, 1, c1s, hnext, 0);
    // cell2: z = [h1_new | h2_prev] @ Wt2^T + b2 -> h2_new, c2
    gemm_bt<<<dim3(32, 16), 256, 0, stream>>>(
        hnext, 1024, 512, hprev + 512, 1024, 512, Wt2, b2,
        nullptr, 0, 0, 1, c2s, hnext, 512);
  }

  // final h2 lives in hB (t=6 even -> hnext == hB)
  gemm_bt<<<dim3(32, 2), 256, 0, stream>>>(
      hB + 512, 1024, 512, (const __hip_bfloat16*)nullptr, 0, 0,
      fcwt, fcb, out, 256, 1, 0, nullptr, nullptr, 0);
}